// Round 4
// baseline (20999.765 us; speedup 1.0000x reference)
//
#include <hip/hip_runtime.h>

typedef unsigned int u32;
typedef unsigned long long u64;
typedef unsigned short u16;
typedef __attribute__((ext_vector_type(8))) short short8;
typedef __attribute__((ext_vector_type(4))) float f32x4;

#define MFMA(a,b,c) __builtin_amdgcn_mfma_f32_16x16x32_bf16((a),(b),(c),0,0,0)
#define ALOAD64(p)    __hip_atomic_load((p), __ATOMIC_RELAXED, __HIP_MEMORY_SCOPE_AGENT)
#define ALOAD32(p)    __hip_atomic_load((p), __ATOMIC_RELAXED, __HIP_MEMORY_SCOPE_AGENT)
#define ASTORE32(p,v) __hip_atomic_store((p),(v), __ATOMIC_RELAXED, __HIP_MEMORY_SCOPE_AGENT)

__device__ __forceinline__ float bf2f(u32 b){ union{u32 u; float f;} v; v.u = b<<16; return v.f; }
__device__ __forceinline__ u16 f2bf(float f){ union{float f; u32 u;} v; v.f = f; u32 u = v.u;
  return (u16)((u + 0x7fffu + ((u>>16)&1u)) >> 16); }
__device__ __forceinline__ u32 pack_f(float v){
  u16 hi = f2bf(v); u16 lo = f2bf(v - bf2f(hi)); return (u32)hi | ((u32)lo<<16); }

__device__ __forceinline__ void unpack8(uint4 a, uint4 b, short8& hi, short8& lo){
  u32 w[8] = {a.x,a.y,a.z,a.w,b.x,b.y,b.z,b.w};
#pragma unroll
  for (int j=0;j<8;++j){ hi[j] = (short)(w[j] & 0xffffu); lo[j] = (short)(w[j] >> 16); }
}
__device__ __forceinline__ void unpackq(u64 q0,u64 q1,u64 q2,u64 q3, short8& hi, short8& lo){
  u32 w[8] = {(u32)q0,(u32)(q0>>32),(u32)q1,(u32)(q1>>32),(u32)q2,(u32)(q2>>32),(u32)q3,(u32)(q3>>32)};
#pragma unroll
  for (int j=0;j<8;++j){ hi[j] = (short)(w[j] & 0xffffu); lo[j] = (short)(w[j] >> 16); }
}

// ---------------- workspace layout (bytes) ----------------
constexpr size_t OFF_Y    = 0;            // u32[1000][32][256]; reused as out2 [250][32][1024]
constexpr size_t OFF_SUB  = 32768000;     // u32[250][32][1024]
constexpr size_t OFF_W0XH = 65536000;
constexpr size_t OFF_W0XL = 67108864;
constexpr size_t OFF_W0HH = 68681728;
constexpr size_t OFF_W0HL = 74973184;
constexpr size_t OFF_W1XH = 81264640;
constexpr size_t OFF_W1XL = 87556096;
constexpr size_t OFF_W1HH = 93847552;
constexpr size_t OFF_W1HL = 100139008;
constexpr size_t HBASE    = 106430464;
constexpr size_t OFF_HA0  = HBASE;                 // u32[2][16][1024] = 131072 B
constexpr size_t OFF_HBB0 = HBASE + 131072;
constexpr size_t OFF_HA1  = HBASE + 262144;
constexpr size_t OFF_HBB1 = HBASE + 393216;
constexpr size_t OFF_FA0  = HBASE + 524288;        // int[256] padded 1KB each
constexpr size_t OFF_FB0  = HBASE + 525312;
constexpr size_t OFF_FA1  = HBASE + 526336;
constexpr size_t OFF_FB1  = HBASE + 527360;
constexpr size_t WS_NEED  = HBASE + 528384;

// ---------------- weight fragment builder (compact 12-col; same as R3) ----------------
// blob: [wg=256][kq=8][kt=K/256][kseg=4][c=12][j=8] u16
// k = kq*(K/8) + kt*32 + kseg*8 + j ; col = (c>>2)*1024 + wg*4 + (c&3)
__global__ void build_frags(const float* __restrict__ W, u16* __restrict__ fhi,
                            u16* __restrict__ flo, int K){
  const int KT = K >> 8;
  size_t total = (size_t)K * 12 * 256;
  for (size_t i = (size_t)blockIdx.x*blockDim.x + threadIdx.x; i < total;
       i += (size_t)gridDim.x*blockDim.x){
    int j = (int)(i & 7); size_t r = i >> 3;
    int c = (int)(r % 12); r /= 12;
    int kseg = (int)(r & 3); r >>= 2;
    int kt = (int)(r % KT); r /= KT;
    int kq = (int)(r & 7); r >>= 3;
    int wg = (int)r;
    int k = kq*(K>>3) + kt*32 + kseg*8 + j;
    int col = (c>>2)*1024 + wg*4 + (c&3);
    float v = W[(size_t)k*3072 + col];
    u16 hi = f2bf(v);
    u16 lo = f2bf(v - bf2f(hi));
    fhi[i] = hi; flo[i] = lo;
  }
}

// ---------------- init h0 + flags ----------------
__global__ void init_state(const float* __restrict__ h0, u32* hA0, u32* hB0,
                           u32* hA1, u32* hB1, int* fa0, int* fb0, int* fa1, int* fb1){
  int i = blockIdx.x*blockDim.x + threadIdx.x;
  if (i < 256){ fa0[i]=0; fb0[i]=0; fa1[i]=0; fb1[i]=0; }
  if (i < 16384){
    u32 p = pack_f(h0[i & 1023]);
    hA0[i] = p; hB0[i] = p;     // slot 0: every sample starts at h0
    hA1[i] = 0u; hB1[i] = 0u;   // layer-1 initial state = 0
  }
}

// ---------------- conv + relu + pack ----------------
__global__ void conv_pack(const float* __restrict__ x, const float* __restrict__ cw,
                          u32* __restrict__ yp){
  for (size_t i = (size_t)blockIdx.x*blockDim.x + threadIdx.x; i < 8192000ull;
       i += (size_t)gridDim.x*blockDim.x){
    int f = (int)(i & 255); int b = (int)((i>>8)&31); int t = (int)(i>>13);
    const float* xb = x + ((size_t)b*1000 + t)*256 + f;
    float acc = xb[0]*cw[256+f];
    if (t > 0)   acc += xb[-256]*cw[f];
    if (t < 999) acc += xb[256]*cw[512+f];
    acc = fmaxf(acc, 0.0f);
    yp[i] = pack_f(acc);
  }
}

// ---------------- persistent GRU layer, batch-split pipelined ----------------
// 256 WGs x 1024 thr (16 waves). WG owns 4 units. Halves: A = samples 0-15,
// B = 16-31, independent recurrences with own flags + 2-slot h buffers.
// Per iter: [recA | finishB(t-1) by wave1 | pollB by wave2] then
//           [recB + xproj(t+1) | finishA(t) by wave0 | pollA(t+1) by wave3].
// All publish/poll LLC round-trips overlap the other half's compute.
template<int LAYER>
__global__ __launch_bounds__(1024, 1)
void gru_persist(const u32* __restrict__ xin,
                 const u16* __restrict__ wxf_hi, const u16* __restrict__ wxf_lo,
                 const u16* __restrict__ whf_hi, const u16* __restrict__ whf_lo,
                 const float* __restrict__ bias,
                 u32* hbA, u32* hbB, int* flA, int* flB, u32* out_pack)
{
  constexpr int T   = (LAYER==0) ? 1000 : 250;
  constexpr int KX  = (LAYER==0) ? 256 : 1024;
  constexpr int KTX = KX >> 8;           // Wx chunks per kq8: 1 or 4
  __shared__ u16 WxHi[8*KTX*512], WxLo[8*KTX*512];
  __shared__ u16 WhHi[8*4*512],  WhLo[8*4*512];
  __shared__ float exch[16*16*19];       // [slot16][row16][19] = 19456 B

  const int tid  = threadIdx.x;
  const int wg   = blockIdx.x;
  const int lane = tid & 63;
  const int wave = tid >> 6;
  const int u0   = wg * 4;
  const int lo16 = lane & 15, hi16 = lane >> 4;
  const int lane_off = hi16*128 + lo16*8;

  { // zero weight LDS (pad cols), then scatter compact blobs (same as R3)
    for (int i = tid; i < 8*KTX*512/4; i += 1024){ ((u64*)WxHi)[i]=0; ((u64*)WxLo)[i]=0; }
    for (int i = tid; i < 8*4*512/4;  i += 1024){ ((u64*)WhHi)[i]=0; ((u64*)WhLo)[i]=0; }
  }
  __syncthreads();
  {
    const u16* bx_hi = wxf_hi + (size_t)wg*KX*12;
    const u16* bx_lo = wxf_lo + (size_t)wg*KX*12;
    const u16* bh_hi = whf_hi + (size_t)wg*1024*12;
    const u16* bh_lo = whf_lo + (size_t)wg*1024*12;
    for (int i = tid; i < 8*KTX*48; i += 1024){
      int c = i % 12; int r = i/12; int kseg = r & 3; r >>= 2;
      int kt = r % KTX; int kqq = r / KTX;
      int ldsoff = ((kqq*KTX+kt)*4+kseg)*128 + c*8;            // [z r xh 0]
      *(short8*)&WxHi[ldsoff] = *(const short8*)&bx_hi[(size_t)i*8];
      *(short8*)&WxLo[ldsoff] = *(const short8*)&bx_lo[(size_t)i*8];
    }
    for (int i = tid; i < 8*4*48; i += 1024){
      int c = i % 12; int r = i/12; int kseg = r & 3; r >>= 2;
      int kt = r & 3; int kqq = r >> 2;
      int cm = (c < 8) ? c : (c + 4);                          // [z r 0 rh]
      int ldsoff = ((kqq*4+kt)*4+kseg)*128 + cm*8;
      *(short8*)&WhHi[ldsoff] = *(const short8*)&bh_hi[(size_t)i*8];
      *(short8*)&WhLo[ldsoff] = *(const short8*)&bh_lo[(size_t)i*8];
    }
  }

  // gate-wave personal state: wave0 owns half A, wave1 owns half B
  const int gs = lane >> 2, gu = lane & 3, eu = u0 + gu;
  const float zb  = bias[eu]        + bias[3072 + eu];
  const float rbv = bias[1024 + eu] + bias[4096 + eu];
  const float hxb = bias[2048 + eu];
  const float hrb = bias[5120 + eu];
  float hreg = 0.f;
  if (wave == 0){ u32 p = hbA[gs*1024 + eu]; hreg = bf2f(p & 0xffffu) + bf2f(p >> 16); }
  if (wave == 1){ u32 p = hbB[gs*1024 + eu]; hreg = bf2f(p & 0xffffu) + bf2f(p >> 16); }
  __syncthreads();

  auto xproj = [&](int th, int half)->f32x4 {
    f32x4 xa = (f32x4){0.f,0.f,0.f,0.f};
    if (LAYER==0 && (wave>>3) != half) return xa;
    const int cb = (LAYER==1) ? wave*2 : (wave&7);
    const u32* xr = xin + ((size_t)th*32 + half*16 + lo16)*KX + cb*32 + hi16*8;
#pragma unroll
    for (int c = 0; c < ((LAYER==1)?2:1); ++c){
      uint4 a0 = *(const uint4*)(xr + c*32);
      uint4 a1 = *(const uint4*)(xr + c*32 + 4);
      short8 ahi, alo; unpack8(a0, a1, ahi, alo);
      short8 bhi = *(const short8*)&WxHi[(cb+c)*512 + lane_off];
      short8 blo = *(const short8*)&WxLo[(cb+c)*512 + lane_off];
      xa = MFMA(ahi, bhi, xa); xa = MFMA(alo, bhi, xa); xa = MFMA(ahi, blo, xa);
    }
    return xa;
  };

  auto recload = [&](const u32* hb, int slot, u64* q){
    const u32* hrow = hb + slot*16384 + lo16*1024 + wave*64 + hi16*8;
#pragma unroll
    for (int i = 0; i < 4; ++i) q[i]   = ALOAD64(((const u64*)hrow) + i);
#pragma unroll
    for (int i = 0; i < 4; ++i) q[4+i] = ALOAD64(((const u64*)(hrow + 32)) + i);
  };
  auto recmm = [&](const u64* q)->f32x4 {
    f32x4 rc = (f32x4){0.f,0.f,0.f,0.f};
#pragma unroll
    for (int kt = 0; kt < 2; ++kt){
      short8 ahi, alo; unpackq(q[kt*4], q[kt*4+1], q[kt*4+2], q[kt*4+3], ahi, alo);
      short8 bhi = *(const short8*)&WhHi[(wave*2+kt)*512 + lane_off];
      short8 blo = *(const short8*)&WhLo[(wave*2+kt)*512 + lane_off];
      rc = MFMA(ahi, bhi, rc); rc = MFMA(alo, bhi, rc); rc = MFMA(ahi, blo, rc);
    }
    return rc;
  };

  auto gates = [&](int ts, int half, u32* hb, int* fl, int flagval, bool publish){
    float zp=0.f, rp=0.f, xh=0.f, rh=0.f;
#pragma unroll
    for (int s = 0; s < 16; ++s){
      const float* e = &exch[s*304 + gs*19];
      zp += e[gu]; rp += e[4+gu]; xh += e[8+gu]; rh += e[12+gu];
    }
    float z = 1.f/(1.f + __expf(-(zp + zb)));
    float r = 1.f/(1.f + __expf(-(rp + rbv)));
    float pre = xh + hxb + r*(rh + hrb);
    float ex = __expf(-2.f*fabsf(pre));
    float th = (1.f - ex)/(1.f + ex);
    float hh = copysignf(th, pre);
    float hn = z*hreg + (1.f - z)*hh;
    hreg = hn;
    u32 pk = pack_f(hn);
    if (publish) ASTORE32(hb + ((ts+1)&1)*16384 + gs*1024 + eu, pk);
    if (LAYER==0){
      if ((ts & 3) == 0) out_pack[((size_t)(ts>>2)*32 + half*16 + gs)*1024 + eu] = pk;
    } else {
      out_pack[((size_t)ts*32 + half*16 + gs)*1024 + eu] = pk;
    }
    if (publish){
      asm volatile("s_waitcnt vmcnt(0)" ::: "memory");   // h (and out) stores acked
      if (lane == 0) ASTORE32(fl + wg, flagval);
    }
  };

  auto poll = [&](const int* fl, int v){
    int a,b,c,d;
    do {
      a = ALOAD32(fl + lane);      b = ALOAD32(fl + 64 + lane);
      c = ALOAD32(fl + 128 + lane); d = ALOAD32(fl + 192 + lane);
    } while (!__all(a >= v && b >= v && c >= v && d >= v));
  };

  f32x4 xaA = xproj(0, 0), xaB = xproj(0, 1);
  for (int t = 0; t < T; ++t){
    const int cur = t & 1;
    // -------- Phase A --------
    u64 qa[8]; recload(hbA, cur, qa);
    if (wave == 1 && t > 0) gates(t-1, 1, hbB, flB, t, true);   // finish B(t-1)
    if (wave == 2 && t > 0) poll(flB, t);                       // hB(t) ready?
    f32x4 ra = recmm(qa);
    __syncthreads();                                            // S1: exch consumed
    {
      const bool fold = (LAYER==1) || (wave < 8);
#pragma unroll
      for (int r4 = 0; r4 < 4; ++r4)
        exch[wave*304 + (hi16*4+r4)*19 + lo16] = ra[r4] + (fold ? xaA[r4] : 0.f);
    }
    __syncthreads();                                            // S2: exchA ready
    // -------- Phase B --------
    u64 qb[8]; recload(hbB, cur, qb);
    if (wave == 0) gates(t, 0, hbA, flA, t+1, true);            // finish A(t)
    if (wave == 3 && t+1 < T) poll(flA, t+1);                   // hA(t+1) ready?
    f32x4 rb = recmm(qb);
    f32x4 xaA_n = (f32x4){0.f,0.f,0.f,0.f}, xaB_n = xaA_n;
    if (t+1 < T){ xaA_n = xproj(t+1, 0); xaB_n = xproj(t+1, 1); }
    __syncthreads();                                            // S3: exchA consumed
    {
      const bool fold = (LAYER==1) || (wave >= 8);
#pragma unroll
      for (int r4 = 0; r4 < 4; ++r4)
        exch[wave*304 + (hi16*4+r4)*19 + lo16] = rb[r4] + (fold ? xaB[r4] : 0.f);
    }
    __syncthreads();                                            // S4: exchB ready
    xaA = xaA_n; xaB = xaB_n;
  }
  // epilogue: B's last step was never consumed in-loop
  if (wave == 1) gates(T-1, 1, hbB, flB, T, false);
}

// ---------------- final dense head ----------------
__global__ __launch_bounds__(256, 1)
void dense_k(const u32* __restrict__ h2, const float* __restrict__ W,
             const float* __restrict__ bias, float* __restrict__ out){
  __shared__ float rows[32*1025];
  const int ts = blockIdx.x;
  const u32* src = h2 + (size_t)ts*32768;
  for (int i = threadIdx.x; i < 32768; i += 256){
    u32 p = src[i];
    rows[(i>>10)*1025 + (i&1023)] = bf2f(p & 0xffffu) + bf2f(p >> 16);
  }
  __syncthreads();
  const int b = threadIdx.x >> 3, cg = threadIdx.x & 7;
  float acc[6] = {0.f,0.f,0.f,0.f,0.f,0.f};
  for (int k = 0; k < 1024; ++k){
    float hv = rows[b*1025 + k];
    const float* wr = W + k*41;
#pragma unroll
    for (int j = 0; j < 6; ++j){ int c = cg + 8*j; if (c < 41) acc[j] += hv*wr[c]; }
  }
#pragma unroll
  for (int j = 0; j < 6; ++j){
    int c = cg + 8*j;
    if (c < 41) out[((size_t)b*250 + ts)*41 + c] = acc[j] + bias[c];
  }
}

// ---------------- launch ----------------
extern "C" void kernel_launch(void* const* d_in, const int* in_sizes, int n_in,
                              void* d_out, int out_size, void* d_ws, size_t ws_size,
                              hipStream_t stream) {
  const float* x      = (const float*)d_in[0];
  const float* conv_w = (const float*)d_in[1];
  const float* h0i    = (const float*)d_in[2];
  const float* w0x    = (const float*)d_in[3];
  const float* w0h    = (const float*)d_in[4];
  const float* b0     = (const float*)d_in[5];
  const float* w1x    = (const float*)d_in[6];
  const float* w1h    = (const float*)d_in[7];
  const float* b1     = (const float*)d_in[8];
  const float* dw     = (const float*)d_in[9];
  const float* db     = (const float*)d_in[10];
  float* outp = (float*)d_out;

  if (ws_size < WS_NEED) return;  // workspace too small: leave output poisoned

  char* ws = (char*)d_ws;
  u32* y_pack   = (u32*)(ws + OFF_Y);
  u32* out2     = (u32*)(ws + OFF_Y);
  u32* sub_pack = (u32*)(ws + OFF_SUB);
  u16* w0x_hi = (u16*)(ws + OFF_W0XH); u16* w0x_lo = (u16*)(ws + OFF_W0XL);
  u16* w0h_hi = (u16*)(ws + OFF_W0HH); u16* w0h_lo = (u16*)(ws + OFF_W0HL);
  u16* w1x_hi = (u16*)(ws + OFF_W1XH); u16* w1x_lo = (u16*)(ws + OFF_W1XL);
  u16* w1h_hi = (u16*)(ws + OFF_W1HH); u16* w1h_lo = (u16*)(ws + OFF_W1HL);
  u32* hA0 = (u32*)(ws + OFF_HA0);  u32* hB0 = (u32*)(ws + OFF_HBB0);
  u32* hA1 = (u32*)(ws + OFF_HA1);  u32* hB1 = (u32*)(ws + OFF_HBB1);
  int* fa0 = (int*)(ws + OFF_FA0);  int* fb0 = (int*)(ws + OFF_FB0);
  int* fa1 = (int*)(ws + OFF_FA1);  int* fb1 = (int*)(ws + OFF_FB1);

  init_state<<<64, 512, 0, stream>>>(h0i, hA0, hB0, hA1, hB1, fa0, fb0, fa1, fb1);
  build_frags<<<2048, 256, 0, stream>>>(w0x, w0x_hi, w0x_lo, 256);
  build_frags<<<2048, 256, 0, stream>>>(w0h, w0h_hi, w0h_lo, 1024);
  build_frags<<<2048, 256, 0, stream>>>(w1x, w1x_hi, w1x_lo, 1024);
  build_frags<<<2048, 256, 0, stream>>>(w1h, w1h_hi, w1h_lo, 1024);
  conv_pack<<<4096, 256, 0, stream>>>(x, conv_w, y_pack);

  gru_persist<0><<<256, 1024, 0, stream>>>(y_pack, w0x_hi, w0x_lo, w0h_hi, w0h_lo,
                                           b0, hA0, hB0, fa0, fb0, sub_pack);
  gru_persist<1><<<256, 1024, 0, stream>>>(sub_pack, w1x_hi, w1x_lo, w1h_hi, w1h_lo,
                                           b1, hA1, hB1, fa1, fb1, out2);

  dense_k<<<250, 256, 0, stream>>>(out2, dw, db, outp);
}

// Round 6
// 14658.656 us; speedup vs baseline: 1.4326x; 1.4326x over previous
//
#include <hip/hip_runtime.h>

typedef unsigned int u32;
typedef unsigned long long u64;
typedef unsigned short u16;
typedef __attribute__((ext_vector_type(8))) short short8;
typedef __attribute__((ext_vector_type(4))) float f32x4;

#define MFMA(a,b,c) __builtin_amdgcn_mfma_f32_16x16x32_bf16((a),(b),(c),0,0,0)
// Agent-scope (LLC) primitives — proven path from R3 for producer->flag chain.
#define ALOAD32(p)    __hip_atomic_load((p), __ATOMIC_RELAXED, __HIP_MEMORY_SCOPE_AGENT)
#define ASTORE32(p,v) __hip_atomic_store((p),(v), __ATOMIC_RELAXED, __HIP_MEMORY_SCOPE_AGENT)
// Workgroup-scope relaxed atomic load: plain cacheable global_load (L1/L2-served),
// but atomic => compiler can't value-forward across iterations/fences.
#define WLOAD64(p)    __hip_atomic_load((p), __ATOMIC_RELAXED, __HIP_MEMORY_SCOPE_WORKGROUP)

__device__ __forceinline__ float bf2f(u32 b){ union{u32 u; float f;} v; v.u = b<<16; return v.f; }
__device__ __forceinline__ u16 f2bf(float f){ union{float f; u32 u;} v; v.f = f; u32 u = v.u;
  return (u16)((u + 0x7fffu + ((u>>16)&1u)) >> 16); }
__device__ __forceinline__ u32 pack_f(float v){
  u16 hi = f2bf(v); u16 lo = f2bf(v - bf2f(hi)); return (u32)hi | ((u32)lo<<16); }

__device__ __forceinline__ void unpack8(uint4 a, uint4 b, short8& hi, short8& lo){
  u32 w[8] = {a.x,a.y,a.z,a.w,b.x,b.y,b.z,b.w};
#pragma unroll
  for (int j=0;j<8;++j){ hi[j] = (short)(w[j] & 0xffffu); lo[j] = (short)(w[j] >> 16); }
}
__device__ __forceinline__ void unpackq(u64 q0,u64 q1,u64 q2,u64 q3, short8& hi, short8& lo){
  u32 w[8] = {(u32)q0,(u32)(q0>>32),(u32)q1,(u32)(q1>>32),(u32)q2,(u32)(q2>>32),(u32)q3,(u32)(q3>>32)};
#pragma unroll
  for (int j=0;j<8;++j){ hi[j] = (short)(w[j] & 0xffffu); lo[j] = (short)(w[j] >> 16); }
}

// ---------------- workspace layout (bytes) — identical to R3 ----------------
constexpr size_t OFF_Y    = 0;            // u32[1000][32][256]; reused as out2 [250][32][1024]
constexpr size_t OFF_SUB  = 32768000;     // u32[250][32][1024]
constexpr size_t OFF_W0XH = 65536000;
constexpr size_t OFF_W0XL = 67108864;
constexpr size_t OFF_W0HH = 68681728;
constexpr size_t OFF_W0HL = 74973184;
constexpr size_t OFF_W1XH = 81264640;
constexpr size_t OFF_W1XL = 87556096;
constexpr size_t OFF_W1HH = 93847552;
constexpr size_t OFF_W1HL = 100139008;
constexpr size_t OFF_HB0  = 106430464;    // u32[2][32][1024] = 262144 B
constexpr size_t OFF_HB1  = 106692608;
constexpr size_t OFF_FL0  = 106954752;    // int[256] pad 1KB
constexpr size_t OFF_FL1  = 106955776;
constexpr size_t WS_NEED  = 106956800;

// ---------------- weight fragment builder (compact 12-col; same as R3) ----------------
// blob: [wg=256][kq=8][kt=K/256][kseg=4][c=12][j=8] u16
// k = kq*(K/8) + kt*32 + kseg*8 + j ; col = (c>>2)*1024 + wg*4 + (c&3)
__global__ void build_frags(const float* __restrict__ W, u16* __restrict__ fhi,
                            u16* __restrict__ flo, int K){
  const int KT = K >> 8;
  size_t total = (size_t)K * 12 * 256;
  for (size_t i = (size_t)blockIdx.x*blockDim.x + threadIdx.x; i < total;
       i += (size_t)gridDim.x*blockDim.x){
    int j = (int)(i & 7); size_t r = i >> 3;
    int c = (int)(r % 12); r /= 12;
    int kseg = (int)(r & 3); r >>= 2;
    int kt = (int)(r % KT); r /= KT;
    int kq = (int)(r & 7); r >>= 3;
    int wg = (int)r;
    int k = kq*(K>>3) + kt*32 + kseg*8 + j;
    int col = (c>>2)*1024 + wg*4 + (c&3);
    float v = W[(size_t)k*3072 + col];
    u16 hi = f2bf(v);
    u16 lo = f2bf(v - bf2f(hi));
    fhi[i] = hi; flo[i] = lo;
  }
}

// ---------------- init h0 + flags ----------------
__global__ void init_state(const float* __restrict__ h0, u32* hb0, u32* hb1,
                           int* f0, int* f1){
  int i = blockIdx.x*blockDim.x + threadIdx.x;
  if (i < 256){ f0[i]=0; f1[i]=0; }
  if (i < 32768){
    int uu = i & 1023;
    hb0[i] = pack_f(h0[uu]);   // slot 0
    hb1[i] = 0u;               // slot 0
  }
}

// ---------------- conv + relu + pack ----------------
__global__ void conv_pack(const float* __restrict__ x, const float* __restrict__ cw,
                          u32* __restrict__ yp){
  for (size_t i = (size_t)blockIdx.x*blockDim.x + threadIdx.x; i < 8192000ull;
       i += (size_t)gridDim.x*blockDim.x){
    int f = (int)(i & 255); int b = (int)((i>>8)&31); int t = (int)(i>>13);
    const float* xb = x + ((size_t)b*1000 + t)*256 + f;
    float acc = xb[0]*cw[256+f];
    if (t > 0)   acc += xb[-256]*cw[f];
    if (t < 999) acc += xb[256]*cw[512+f];
    acc = fmaxf(acc, 0.0f);
    yp[i] = pack_f(acc);
  }
}

// ---------------- persistent GRU layer (R3 + acquire-fence L2-cached broadcast) ----------------
// 256 WGs x 1024 threads. WG owns 4 units. Weights fully LDS-resident.
// Producers: agent h-stores -> vmcnt(0) -> agent flag store  (proven R3 path).
// Consumers: relaxed agent poll -> ONE agent acquire fence (buffer_inv: L1+L2)
// -> cacheable h loads. First WG per XCD misses to LLC, populates local L2;
// remaining 31 WGs hit L2. LLC h-traffic ~32MB/step -> ~1MB/step.
template<int LAYER>
__global__ __launch_bounds__(1024, 1)
void gru_persist(const u32* __restrict__ xin,
                 const u16* __restrict__ wxf_hi, const u16* __restrict__ wxf_lo,
                 const u16* __restrict__ whf_hi, const u16* __restrict__ whf_lo,
                 const float* __restrict__ bias,
                 u32* hbuf, int* flags, u32* out_pack)
{
  constexpr int T   = (LAYER==0) ? 1000 : 250;
  constexpr int KX  = (LAYER==0) ? 256 : 1024;
  constexpr int KTX = KX >> 8;
  __shared__ u16 WxHi[8*KTX*512], WxLo[8*KTX*512];
  __shared__ u16 WhHi[8*4*512],  WhLo[8*4*512];
  __shared__ float exch[8*32*18];
  __shared__ float harr[128];

  const int tid  = threadIdx.x;
  const int wg   = blockIdx.x;
  const int lane = tid & 63;
  const int wave = tid >> 6;
  const int m    = wave & 1;
  const int kq   = wave >> 1;
  const int u0   = wg * 4;
  const int lo16 = lane & 15, hi16 = lane >> 4;
  const int lane_off = hi16*128 + lo16*8;

  { // zero weight LDS (pad cols)
    for (int i = tid; i < 8*KTX*512/4; i += 1024){ ((u64*)WxHi)[i]=0; ((u64*)WxLo)[i]=0; }
    for (int i = tid; i < 8*4*512/4;  i += 1024){ ((u64*)WhHi)[i]=0; ((u64*)WhLo)[i]=0; }
  }
  __syncthreads();
  { // scatter compact blobs into padded LDS tiles (identical to R3)
    const u16* bx_hi = wxf_hi + (size_t)wg*KX*12;
    const u16* bx_lo = wxf_lo + (size_t)wg*KX*12;
    const u16* bh_hi = whf_hi + (size_t)wg*1024*12;
    const u16* bh_lo = whf_lo + (size_t)wg*1024*12;
    for (int i = tid; i < 8*KTX*48; i += 1024){
      int c = i % 12; int r = i/12; int kseg = r & 3; r >>= 2;
      int kt = r % KTX; int kqq = r / KTX;
      int ldsoff = ((kqq*KTX+kt)*4+kseg)*128 + c*8;            // [z r xh 0]
      *(short8*)&WxHi[ldsoff] = *(const short8*)&bx_hi[(size_t)i*8];
      *(short8*)&WxLo[ldsoff] = *(const short8*)&bx_lo[(size_t)i*8];
    }
    for (int i = tid; i < 8*4*48; i += 1024){
      int c = i % 12; int r = i/12; int kseg = r & 3; r >>= 2;
      int kt = r & 3; int kqq = r >> 2;
      int cm = (c < 8) ? c : (c + 4);                          // [z r 0 rh]
      int ldsoff = ((kqq*4+kt)*4+kseg)*128 + cm*8;
      *(short8*)&WhHi[ldsoff] = *(const short8*)&bh_hi[(size_t)i*8];
      *(short8*)&WhLo[ldsoff] = *(const short8*)&bh_lo[(size_t)i*8];
    }
    if (tid < 128){
      u32 p = hbuf[(tid>>2)*1024 + u0 + (tid&3)];              // slot 0 (prev kernel wrote)
      harr[tid] = bf2f(p & 0xffffu) + bf2f(p >> 16);
    }
  }
  __syncthreads();

  const int eb = tid >> 2, eu_l = tid & 3, eu = u0 + eu_l;
  const float zb  = bias[eu]        + bias[3072 + eu];
  const float rbv = bias[1024 + eu] + bias[4096 + eu];
  const float hxb = bias[2048 + eu];
  const float hrb = bias[5120 + eu];

  for (int t = 0; t < T; ++t) {
    const int cur = t & 1, nxt = cur ^ 1;
    f32x4 xacc = (f32x4){0.f,0.f,0.f,0.f};
    f32x4 racc = (f32x4){0.f,0.f,0.f,0.f};
    { // xproj (h-independent; overlaps laggard flag propagation)
      const u32* xrow = xin + ((size_t)t*32 + 16*m + lo16)*KX + kq*(KX>>3) + hi16*8;
#pragma unroll
      for (int kt = 0; kt < KTX; ++kt) {
        uint4 a0 = *(const uint4*)(xrow + kt*32);
        uint4 a1 = *(const uint4*)(xrow + kt*32 + 4);
        short8 ahi, alo; unpack8(a0, a1, ahi, alo);
        short8 bhi = *(const short8*)&WxHi[(kq*KTX+kt)*512 + lane_off];
        short8 blo = *(const short8*)&WxLo[(kq*KTX+kt)*512 + lane_off];
        xacc = MFMA(ahi, bhi, xacc);
        xacc = MFMA(alo, bhi, xacc);
        xacc = MFMA(ahi, blo, xacc);
      }
    }
    // wait for h_t: wave 0 polls (relaxed agent), then one acquire fence
    // (buffer_inv -> invalidates stale L1+L2) before cacheable h loads.
    if (t > 0) {
      if (wave == 0) {
        int f0,f1,f2,f3;
        do {
          f0 = ALOAD32(flags + lane);       f1 = ALOAD32(flags + 64 + lane);
          f2 = ALOAD32(flags + 128 + lane); f3 = ALOAD32(flags + 192 + lane);
        } while (!__all(f0 >= t && f1 >= t && f2 >= t && f3 >= t));
        __builtin_amdgcn_fence(__ATOMIC_ACQUIRE, "agent");
      }
      __syncthreads();
    }
    { // recurrent: h(t) slice @ Wh tile — CACHEABLE loads (L2-served per XCD)
      const u32* hrow = hbuf + cur*32768 + (16*m + lo16)*1024 + kq*128 + hi16*8;
      u64 q[16];
#pragma unroll
      for (int kt = 0; kt < 4; ++kt){
        const u64* hq = (const u64*)(hrow + kt*32);
#pragma unroll
        for (int j = 0; j < 4; ++j) q[kt*4+j] = WLOAD64(hq + j);
      }
#pragma unroll
      for (int kt = 0; kt < 4; ++kt) {
        short8 ahi, alo; unpackq(q[kt*4], q[kt*4+1], q[kt*4+2], q[kt*4+3], ahi, alo);
        short8 bhi = *(const short8*)&WhHi[(kq*4+kt)*512 + lane_off];
        short8 blo = *(const short8*)&WhLo[(kq*4+kt)*512 + lane_off];
        racc = MFMA(ahi, bhi, racc);
        racc = MFMA(alo, bhi, racc);
        racc = MFMA(ahi, blo, racc);
      }
    }
    { // exchange partials: D layout col=lane&15, row=(lane>>4)*4+r
      const int bb = 16*m + hi16*4;
#pragma unroll
      for (int r4 = 0; r4 < 4; ++r4)
        exch[(kq*32 + bb + r4)*18 + lo16] = xacc[r4] + racc[r4];
    }
    __syncthreads();
    if (tid < 128) { // gates: one (b,unit) per thread
      float zp=0.f, rp=0.f, xh=0.f, rh=0.f;
#pragma unroll
      for (int qd = 0; qd < 8; ++qd) {
        const float* e = &exch[(qd*32 + eb)*18];
        zp += e[eu_l];
        rp += e[4 + eu_l];
        xh += e[8 + eu_l];
        rh += e[12 + eu_l];
      }
      float z = 1.f/(1.f + __expf(-(zp + zb)));
      float r = 1.f/(1.f + __expf(-(rp + rbv)));
      float pre = xh + hxb + r*(rh + hrb);
      float ex = __expf(-2.f*fabsf(pre));
      float th = (1.f - ex)/(1.f + ex);
      float hh = copysignf(th, pre);
      float hn = z*harr[tid] + (1.f - z)*hh;
      harr[tid] = hn;
      u32 pk = pack_f(hn);
      ASTORE32(hbuf + nxt*32768 + eb*1024 + u0 + eu_l, pk);
      if (LAYER==0) {
        if ((t & 3) == 0)
          out_pack[((size_t)(t>>2)*32 + eb)*1024 + u0 + eu_l] = pk;
      } else {
        out_pack[((size_t)t*32 + eb)*1024 + u0 + eu_l] = pk;
      }
    }
    asm volatile("s_waitcnt vmcnt(0)" ::: "memory");   // own stores committed
    __syncthreads();                                   // => whole WG's stores committed
    if (tid == 0)
      ASTORE32(flags + wg, t+1);
  }
}

// ---------------- final dense head ----------------
__global__ __launch_bounds__(256, 1)
void dense_k(const u32* __restrict__ h2, const float* __restrict__ W,
             const float* __restrict__ bias, float* __restrict__ out){
  __shared__ float rows[32*1025];
  const int ts = blockIdx.x;
  const u32* src = h2 + (size_t)ts*32768;
  for (int i = threadIdx.x; i < 32768; i += 256){
    u32 p = src[i];
    rows[(i>>10)*1025 + (i&1023)] = bf2f(p & 0xffffu) + bf2f(p >> 16);
  }
  __syncthreads();
  const int b = threadIdx.x >> 3, cg = threadIdx.x & 7;
  float acc[6] = {0.f,0.f,0.f,0.f,0.f,0.f};
  for (int k = 0; k < 1024; ++k){
    float hv = rows[b*1025 + k];
    const float* wr = W + k*41;
#pragma unroll
    for (int j = 0; j < 6; ++j){ int c = cg + 8*j; if (c < 41) acc[j] += hv*wr[c]; }
  }
#pragma unroll
  for (int j = 0; j < 6; ++j){
    int c = cg + 8*j;
    if (c < 41) out[((size_t)b*250 + ts)*41 + c] = acc[j] + bias[c];
  }
}

// ---------------- launch ----------------
extern "C" void kernel_launch(void* const* d_in, const int* in_sizes, int n_in,
                              void* d_out, int out_size, void* d_ws, size_t ws_size,
                              hipStream_t stream) {
  const float* x      = (const float*)d_in[0];
  const float* conv_w = (const float*)d_in[1];
  const float* h0i    = (const float*)d_in[2];
  const float* w0x    = (const float*)d_in[3];
  const float* w0h    = (const float*)d_in[4];
  const float* b0     = (const float*)d_in[5];
  const float* w1x    = (const float*)d_in[6];
  const float* w1h    = (const float*)d_in[7];
  const float* b1     = (const float*)d_in[8];
  const float* dw     = (const float*)d_in[9];
  const float* db     = (const float*)d_in[10];
  float* outp = (float*)d_out;

  if (ws_size < WS_NEED) return;  // workspace too small: leave output poisoned

  char* ws = (char*)d_ws;
  u32* y_pack   = (u32*)(ws + OFF_Y);
  u32* out2     = (u32*)(ws + OFF_Y);
  u32* sub_pack = (u32*)(ws + OFF_SUB);
  u16* w0x_hi = (u16*)(ws + OFF_W0XH); u16* w0x_lo = (u16*)(ws + OFF_W0XL);
  u16* w0h_hi = (u16*)(ws + OFF_W0HH); u16* w0h_lo = (u16*)(ws + OFF_W0HL);
  u16* w1x_hi = (u16*)(ws + OFF_W1XH); u16* w1x_lo = (u16*)(ws + OFF_W1XL);
  u16* w1h_hi = (u16*)(ws + OFF_W1HH); u16* w1h_lo = (u16*)(ws + OFF_W1HL);
  u32* hb0 = (u32*)(ws + OFF_HB0);
  u32* hb1 = (u32*)(ws + OFF_HB1);
  int* fl0 = (int*)(ws + OFF_FL0);
  int* fl1 = (int*)(ws + OFF_FL1);

  init_state<<<64, 512, 0, stream>>>(h0i, hb0, hb1, fl0, fl1);
  build_frags<<<2048, 256, 0, stream>>>(w0x, w0x_hi, w0x_lo, 256);
  build_frags<<<2048, 256, 0, stream>>>(w0h, w0h_hi, w0h_lo, 1024);
  build_frags<<<2048, 256, 0, stream>>>(w1x, w1x_hi, w1x_lo, 1024);
  build_frags<<<2048, 256, 0, stream>>>(w1h, w1h_hi, w1h_lo, 1024);
  conv_pack<<<4096, 256, 0, stream>>>(x, conv_w, y_pack);

  gru_persist<0><<<256, 1024, 0, stream>>>(y_pack, w0x_hi, w0x_lo, w0h_hi, w0h_lo,
                                           b0, hb0, fl0, sub_pack);
  gru_persist<1><<<256, 1024, 0, stream>>>(sub_pack, w1x_hi, w1x_lo, w1h_hi, w1h_lo,
                                           b1, hb1, fl1, out2);

  dense_k<<<250, 256, 0, stream>>>(out2, dw, db, outp);
}

// Round 9
// 13486.349 us; speedup vs baseline: 1.5571x; 1.0869x over previous
//
#include <hip/hip_runtime.h>

typedef unsigned int u32;
typedef unsigned long long u64;
typedef unsigned short u16;
typedef __attribute__((ext_vector_type(8))) short short8;
typedef __attribute__((ext_vector_type(4))) float f32x4;

#define MFMA(a,b,c) __builtin_amdgcn_mfma_f32_16x16x32_bf16((a),(b),(c),0,0,0)
// Agent-scope (LLC) primitives — proven R3 path.
#define ALOAD64(p)    __hip_atomic_load((p), __ATOMIC_RELAXED, __HIP_MEMORY_SCOPE_AGENT)
#define ALOAD32(p)    __hip_atomic_load((p), __ATOMIC_RELAXED, __HIP_MEMORY_SCOPE_AGENT)
#define ASTORE32(p,v) __hip_atomic_store((p),(v), __ATOMIC_RELAXED, __HIP_MEMORY_SCOPE_AGENT)

__device__ __forceinline__ float bf2f(u32 b){ union{u32 u; float f;} v; v.u = b<<16; return v.f; }
__device__ __forceinline__ u16 f2bf(float f){ union{float f; u32 u;} v; v.f = f; u32 u = v.u;
  return (u16)((u + 0x7fffu + ((u>>16)&1u)) >> 16); }
__device__ __forceinline__ u32 pack_f(float v){
  u16 hi = f2bf(v); u16 lo = f2bf(v - bf2f(hi)); return (u32)hi | ((u32)lo<<16); }

__device__ __forceinline__ void unpack8(uint4 a, uint4 b, short8& hi, short8& lo){
  u32 w[8] = {a.x,a.y,a.z,a.w,b.x,b.y,b.z,b.w};
#pragma unroll
  for (int j=0;j<8;++j){ hi[j] = (short)(w[j] & 0xffffu); lo[j] = (short)(w[j] >> 16); }
}
__device__ __forceinline__ void unpackq(u64 q0,u64 q1,u64 q2,u64 q3, short8& hi, short8& lo){
  u32 w[8] = {(u32)q0,(u32)(q0>>32),(u32)q1,(u32)(q1>>32),(u32)q2,(u32)(q2>>32),(u32)q3,(u32)(q3>>32)};
#pragma unroll
  for (int j=0;j<8;++j){ hi[j] = (short)(w[j] & 0xffffu); lo[j] = (short)(w[j] >> 16); }
}

// ---------------- workspace layout (bytes) — identical to R3 ----------------
constexpr size_t OFF_Y    = 0;            // u32[1000][32][256]; reused as out2 [250][32][1024]
constexpr size_t OFF_SUB  = 32768000;     // u32[250][32][1024]
constexpr size_t OFF_W0XH = 65536000;
constexpr size_t OFF_W0XL = 67108864;
constexpr size_t OFF_W0HH = 68681728;
constexpr size_t OFF_W0HL = 74973184;
constexpr size_t OFF_W1XH = 81264640;
constexpr size_t OFF_W1XL = 87556096;
constexpr size_t OFF_W1HH = 93847552;
constexpr size_t OFF_W1HL = 100139008;
constexpr size_t OFF_HB0  = 106430464;    // u32[2][32][1024] = 262144 B
constexpr size_t OFF_HB1  = 106692608;
constexpr size_t OFF_FL0  = 106954752;    // int[256] pad 1KB
constexpr size_t OFF_FL1  = 106955776;
constexpr size_t WS_NEED  = 106956800;

// ---------------- weight fragment builder (compact 12-col; R3-proven) ----------------
// blob: [wg=256][kq=8][kt=K/256][kseg=4][c=12][j=8] u16
// k = kq*(K/8) + kt*32 + kseg*8 + j ; col = (c>>2)*1024 + wg*4 + (c&3)
__global__ void build_frags(const float* __restrict__ W, u16* __restrict__ fhi,
                            u16* __restrict__ flo, int K){
  const int KT = K >> 8;
  size_t total = (size_t)K * 12 * 256;
  for (size_t i = (size_t)blockIdx.x*blockDim.x + threadIdx.x; i < total;
       i += (size_t)gridDim.x*blockDim.x){
    int j = (int)(i & 7); size_t r = i >> 3;
    int c = (int)(r % 12); r /= 12;
    int kseg = (int)(r & 3); r >>= 2;
    int kt = (int)(r % KT); r /= KT;
    int kq = (int)(r & 7); r >>= 3;
    int wg = (int)r;
    int k = kq*(K>>3) + kt*32 + kseg*8 + j;
    int col = (c>>2)*1024 + wg*4 + (c&3);
    float v = W[(size_t)k*3072 + col];
    u16 hi = f2bf(v);
    u16 lo = f2bf(v - bf2f(hi));
    fhi[i] = hi; flo[i] = lo;
  }
}

// ---------------- init h0 + flags ----------------
__global__ void init_state(const float* __restrict__ h0, u32* hb0, u32* hb1,
                           int* f0, int* f1){
  int i = blockIdx.x*blockDim.x + threadIdx.x;
  if (i < 256){ f0[i]=0; f1[i]=0; }
  if (i < 32768){
    int uu = i & 1023;
    hb0[i] = pack_f(h0[uu]);   // slot 0
    hb1[i] = 0u;               // slot 0
  }
}

// ---------------- conv + relu + pack ----------------
__global__ void conv_pack(const float* __restrict__ x, const float* __restrict__ cw,
                          u32* __restrict__ yp){
  for (size_t i = (size_t)blockIdx.x*blockDim.x + threadIdx.x; i < 8192000ull;
       i += (size_t)gridDim.x*blockDim.x){
    int f = (int)(i & 255); int b = (int)((i>>8)&31); int t = (int)(i>>13);
    const float* xb = x + ((size_t)b*1000 + t)*256 + f;
    float acc = xb[0]*cw[256+f];
    if (t > 0)   acc += xb[-256]*cw[f];
    if (t < 999) acc += xb[256]*cw[512+f];
    acc = fmaxf(acc, 0.0f);
    yp[i] = pack_f(acc);
  }
}

// ---------------- persistent GRU layer (R3 + per-wave quarter poll + wave0 gates) ----------------
// 256 WGs x 1024 threads. WG owns 4 units. Weights fully LDS-resident.
// Wave kq consumes h units [kq*128,(kq+1)*128), produced exactly by WGs
// [32kq,32kq+32) -> wave polls ONLY those 32 flags, then immediately h-loads.
// 2-slot safety: a WG's h-write happens after its exch barrier, which requires
// all 16 waves past their quarter waits >= t  =>  all 256 flags >= t  =>  all
// WGs finished step t-1 and their reads of the slot being overwritten (R3 invariant).
// Gates+publish in wave 0 only: h stores -> wave0 vmcnt(0) -> flag, no barrier
// on the publish path.
template<int LAYER>
__global__ __launch_bounds__(1024, 1)
void gru_persist(const u32* __restrict__ xin,
                 const u16* __restrict__ wxf_hi, const u16* __restrict__ wxf_lo,
                 const u16* __restrict__ whf_hi, const u16* __restrict__ whf_lo,
                 const float* __restrict__ bias,
                 u32* hbuf, int* flags, u32* out_pack)
{
  constexpr int T   = (LAYER==0) ? 1000 : 250;
  constexpr int KX  = (LAYER==0) ? 256 : 1024;
  constexpr int KTX = KX >> 8;
  __shared__ u16 WxHi[8*KTX*512], WxLo[8*KTX*512];
  __shared__ u16 WhHi[8*4*512],  WhLo[8*4*512];
  __shared__ float exch[8*32*18];

  const int tid  = threadIdx.x;
  const int wg   = blockIdx.x;
  const int lane = tid & 63;
  const int wave = tid >> 6;
  const int m    = wave & 1;
  const int kq   = wave >> 1;
  const int u0   = wg * 4;
  const int lo16 = lane & 15, hi16 = lane >> 4;
  const int lane_off = hi16*128 + lo16*8;

  { // zero weight LDS (pad cols)
    for (int i = tid; i < 8*KTX*512/4; i += 1024){ ((u64*)WxHi)[i]=0; ((u64*)WxLo)[i]=0; }
    for (int i = tid; i < 8*4*512/4;  i += 1024){ ((u64*)WhHi)[i]=0; ((u64*)WhLo)[i]=0; }
  }
  __syncthreads();
  { // scatter compact blobs into padded LDS tiles (identical to R3)
    const u16* bx_hi = wxf_hi + (size_t)wg*KX*12;
    const u16* bx_lo = wxf_lo + (size_t)wg*KX*12;
    const u16* bh_hi = whf_hi + (size_t)wg*1024*12;
    const u16* bh_lo = whf_lo + (size_t)wg*1024*12;
    for (int i = tid; i < 8*KTX*48; i += 1024){
      int c = i % 12; int r = i/12; int kseg = r & 3; r >>= 2;
      int kt = r % KTX; int kqq = r / KTX;
      int ldsoff = ((kqq*KTX+kt)*4+kseg)*128 + c*8;            // [z r xh 0]
      *(short8*)&WxHi[ldsoff] = *(const short8*)&bx_hi[(size_t)i*8];
      *(short8*)&WxLo[ldsoff] = *(const short8*)&bx_lo[(size_t)i*8];
    }
    for (int i = tid; i < 8*4*48; i += 1024){
      int c = i % 12; int r = i/12; int kseg = r & 3; r >>= 2;
      int kt = r & 3; int kqq = r >> 2;
      int cm = (c < 8) ? c : (c + 4);                          // [z r 0 rh]
      int ldsoff = ((kqq*4+kt)*4+kseg)*128 + cm*8;
      *(short8*)&WhHi[ldsoff] = *(const short8*)&bh_hi[(size_t)i*8];
      *(short8*)&WhLo[ldsoff] = *(const short8*)&bh_lo[(size_t)i*8];
    }
  }

  // wave0 gate state: 2 items/lane (gt = lane, lane+64), all in registers.
  float hr0 = 0.f, hr1 = 0.f;
  float zb0=0.f, rb0=0.f, hxb0=0.f, hrb0=0.f;
  float zb1=0.f, rb1=0.f, hxb1=0.f, hrb1=0.f;
  if (wave == 0){
    const int euA = u0 + (lane & 3);
    zb0  = bias[euA]        + bias[3072 + euA];
    rb0  = bias[1024 + euA] + bias[4096 + euA];
    hxb0 = bias[2048 + euA];
    hrb0 = bias[5120 + euA];
    zb1 = zb0; rb1 = rb0; hxb1 = hxb0; hrb1 = hrb0;   // same unit, different sample
    u32 pA = hbuf[(lane>>2)*1024 + euA];
    u32 pB = hbuf[((lane+64)>>2)*1024 + euA];
    hr0 = bf2f(pA & 0xffffu) + bf2f(pA >> 16);
    hr1 = bf2f(pB & 0xffffu) + bf2f(pB >> 16);
  }
  __syncthreads();

  for (int t = 0; t < T; ++t) {
    const int cur = t & 1, nxt = cur ^ 1;
    f32x4 xacc = (f32x4){0.f,0.f,0.f,0.f};
    f32x4 racc = (f32x4){0.f,0.f,0.f,0.f};
    { // xproj (h-independent; overlaps laggard flag propagation)
      const u32* xrow = xin + ((size_t)t*32 + 16*m + lo16)*KX + kq*(KX>>3) + hi16*8;
#pragma unroll
      for (int kt = 0; kt < KTX; ++kt) {
        uint4 a0 = *(const uint4*)(xrow + kt*32);
        uint4 a1 = *(const uint4*)(xrow + kt*32 + 4);
        short8 ahi, alo; unpack8(a0, a1, ahi, alo);
        short8 bhi = *(const short8*)&WxHi[(kq*KTX+kt)*512 + lane_off];
        short8 blo = *(const short8*)&WxLo[(kq*KTX+kt)*512 + lane_off];
        xacc = MFMA(ahi, bhi, xacc);
        xacc = MFMA(alo, bhi, xacc);
        xacc = MFMA(ahi, blo, xacc);
      }
    }
    // per-wave wait: only this wave's producer quarter (WGs [32kq,32kq+32))
    if (t > 0) {
      int fv;
      do { fv = ALOAD32(flags + kq*32 + (lane & 31)); } while (__all(fv >= t) == 0);
      asm volatile("" ::: "memory");   // pin h loads behind the poll
    }
    { // recurrent: h(t) quarter @ Wh tile (agent loads, proven-coherent)
      const u32* hrow = hbuf + cur*32768 + (16*m + lo16)*1024 + kq*128 + hi16*8;
      u64 q[16];
#pragma unroll
      for (int kt = 0; kt < 4; ++kt){
        const u64* hq = (const u64*)(hrow + kt*32);
#pragma unroll
        for (int j = 0; j < 4; ++j) q[kt*4+j] = ALOAD64(hq + j);
      }
#pragma unroll
      for (int kt = 0; kt < 4; ++kt) {
        short8 ahi, alo; unpackq(q[kt*4], q[kt*4+1], q[kt*4+2], q[kt*4+3], ahi, alo);
        short8 bhi = *(const short8*)&WhHi[(kq*4+kt)*512 + lane_off];
        short8 blo = *(const short8*)&WhLo[(kq*4+kt)*512 + lane_off];
        racc = MFMA(ahi, bhi, racc);
        racc = MFMA(alo, bhi, racc);
        racc = MFMA(ahi, blo, racc);
      }
    }
    { // exchange partials: D layout col=lane&15, row=(lane>>4)*4+r
      const int bb = 16*m + hi16*4;
#pragma unroll
      for (int r4 = 0; r4 < 4; ++r4)
        exch[(kq*32 + bb + r4)*18 + lo16] = xacc[r4] + racc[r4];
    }
    __syncthreads();                         // exch ready (also: all waves past wait >= t)
    if (wave == 0) { // gates: 2 (sample,unit) items per lane; publish w/o barrier
      const int eu_l = lane & 3;
      const int ebA = lane >> 2, ebB = 16 + (lane >> 2);
      float zpA=0.f, rpA=0.f, xhA=0.f, rhA=0.f;
      float zpB=0.f, rpB=0.f, xhB=0.f, rhB=0.f;
#pragma unroll
      for (int qd = 0; qd < 8; ++qd) {
        const float* eA = &exch[(qd*32 + ebA)*18];
        const float* eB = &exch[(qd*32 + ebB)*18];
        zpA += eA[eu_l];      zpB += eB[eu_l];
        rpA += eA[4 + eu_l];  rpB += eB[4 + eu_l];
        xhA += eA[8 + eu_l];  xhB += eB[8 + eu_l];
        rhA += eA[12 + eu_l]; rhB += eB[12 + eu_l];
      }
      const int eu = u0 + eu_l;
      {
        float z = 1.f/(1.f + __expf(-(zpA + zb0)));
        float r = 1.f/(1.f + __expf(-(rpA + rb0)));
        float pre = xhA + hxb0 + r*(rhA + hrb0);
        float ex = __expf(-2.f*fabsf(pre));
        float th = (1.f - ex)/(1.f + ex);
        float hh = copysignf(th, pre);
        float hn = z*hr0 + (1.f - z)*hh;
        hr0 = hn;
        u32 pk = pack_f(hn);
        ASTORE32(hbuf + nxt*32768 + ebA*1024 + eu, pk);
        if (LAYER==0) { if ((t & 3) == 0)
            out_pack[((size_t)(t>>2)*32 + ebA)*1024 + eu] = pk;
        } else out_pack[((size_t)t*32 + ebA)*1024 + eu] = pk;
      }
      {
        float z = 1.f/(1.f + __expf(-(zpB + zb1)));
        float r = 1.f/(1.f + __expf(-(rpB + rb1)));
        float pre = xhB + hxb1 + r*(rhB + hrb1);
        float ex = __expf(-2.f*fabsf(pre));
        float th = (1.f - ex)/(1.f + ex);
        float hh = copysignf(th, pre);
        float hn = z*hr1 + (1.f - z)*hh;
        hr1 = hn;
        u32 pk = pack_f(hn);
        ASTORE32(hbuf + nxt*32768 + ebB*1024 + eu, pk);
        if (LAYER==0) { if ((t & 3) == 0)
            out_pack[((size_t)(t>>2)*32 + ebB)*1024 + eu] = pk;
        } else out_pack[((size_t)t*32 + ebB)*1024 + eu] = pk;
      }
      asm volatile("s_waitcnt vmcnt(0)" ::: "memory");   // wave0's h stores acked at LLC
      if (lane == 0) ASTORE32(flags + wg, t+1);          // publish immediately
    }
    __syncthreads();                         // exch consumed; close iteration
  }
}

// ---------------- final dense head ----------------
__global__ __launch_bounds__(256, 1)
void dense_k(const u32* __restrict__ h2, const float* __restrict__ W,
             const float* __restrict__ bias, float* __restrict__ out){
  __shared__ float rows[32*1025];
  const int ts = blockIdx.x;
  const u32* src = h2 + (size_t)ts*32768;
  for (int i = threadIdx.x; i < 32768; i += 256){
    u32 p = src[i];
    rows[(i>>10)*1025 + (i&1023)] = bf2f(p & 0xffffu) + bf2f(p >> 16);
  }
  __syncthreads();
  const int b = threadIdx.x >> 3, cg = threadIdx.x & 7;
  float acc[6] = {0.f,0.f,0.f,0.f,0.f,0.f};
  for (int k = 0; k < 1024; ++k){
    float hv = rows[b*1025 + k];
    const float* wr = W + k*41;
#pragma unroll
    for (int j = 0; j < 6; ++j){ int c = cg + 8*j; if (c < 41) acc[j] += hv*wr[c]; }
  }
#pragma unroll
  for (int j = 0; j < 6; ++j){
    int c = cg + 8*j;
    if (c < 41) out[((size_t)b*250 + ts)*41 + c] = acc[j] + bias[c];
  }
}

// ---------------- launch ----------------
extern "C" void kernel_launch(void* const* d_in, const int* in_sizes, int n_in,
                              void* d_out, int out_size, void* d_ws, size_t ws_size,
                              hipStream_t stream) {
  const float* x      = (const float*)d_in[0];
  const float* conv_w = (const float*)d_in[1];
  const float* h0i    = (const float*)d_in[2];
  const float* w0x    = (const float*)d_in[3];
  const float* w0h    = (const float*)d_in[4];
  const float* b0     = (const float*)d_in[5];
  const float* w1x    = (const float*)d_in[6];
  const float* w1h    = (const float*)d_in[7];
  const float* b1     = (const float*)d_in[8];
  const float* dw     = (const float*)d_in[9];
  const float* db     = (const float*)d_in[10];
  float* outp = (float*)d_out;

  if (ws_size < WS_NEED) return;  // workspace too small: leave output poisoned

  char* ws = (char*)d_ws;
  u32* y_pack   = (u32*)(ws + OFF_Y);
  u32* out2     = (u32*)(ws + OFF_Y);      // reuse after y_pack is dead
  u32* sub_pack = (u32*)(ws + OFF_SUB);
  u16* w0x_hi = (u16*)(ws + OFF_W0XH); u16* w0x_lo = (u16*)(ws + OFF_W0XL);
  u16* w0h_hi = (u16*)(ws + OFF_W0HH); u16* w0h_lo = (u16*)(ws + OFF_W0HL);
  u16* w1x_hi = (u16*)(ws + OFF_W1XH); u16* w1x_lo = (u16*)(ws + OFF_W1XL);
  u16* w1h_hi = (u16*)(ws + OFF_W1HH); u16* w1h_lo = (u16*)(ws + OFF_W1HL);
  u32* hb0 = (u32*)(ws + OFF_HB0);
  u32* hb1 = (u32*)(ws + OFF_HB1);
  int* fl0 = (int*)(ws + OFF_FL0);
  int* fl1 = (int*)(ws + OFF_FL1);

  init_state<<<64, 512, 0, stream>>>(h0i, hb0, hb1, fl0, fl1);
  build_frags<<<2048, 256, 0, stream>>>(w0x, w0x_hi, w0x_lo, 256);
  build_frags<<<2048, 256, 0, stream>>>(w0h, w0h_hi, w0h_lo, 1024);
  build_frags<<<2048, 256, 0, stream>>>(w1x, w1x_hi, w1x_lo, 1024);
  build_frags<<<2048, 256, 0, stream>>>(w1h, w1h_hi, w1h_lo, 1024);
  conv_pack<<<4096, 256, 0, stream>>>(x, conv_w, y_pack);

  gru_persist<0><<<256, 1024, 0, stream>>>(y_pack, w0x_hi, w0x_lo, w0h_hi, w0h_lo,
                                           b0, hb0, fl0, sub_pack);
  gru_persist<1><<<256, 1024, 0, stream>>>(sub_pack, w1x_hi, w1x_lo, w1h_hi, w1h_lo,
                                           b1, hb1, fl1, out2);

  dense_k<<<250, 256, 0, stream>>>(out2, dw, db, outp);
}

// Round 10
// 8569.043 us; speedup vs baseline: 2.4507x; 1.5738x over previous
//
#include <hip/hip_runtime.h>

typedef unsigned int u32;
typedef unsigned long long u64;
typedef unsigned short u16;
typedef __attribute__((ext_vector_type(8))) short short8;
typedef __attribute__((ext_vector_type(4))) float f32x4;

#define MFMA(a,b,c) __builtin_amdgcn_mfma_f32_16x16x32_bf16((a),(b),(c),0,0,0)
// Agent-scope (LLC) primitives — proven R3 path.
#define ALOAD64(p)    __hip_atomic_load((p), __ATOMIC_RELAXED, __HIP_MEMORY_SCOPE_AGENT)
#define ALOAD32(p)    __hip_atomic_load((p), __ATOMIC_RELAXED, __HIP_MEMORY_SCOPE_AGENT)
#define ASTORE32(p,v) __hip_atomic_store((p),(v), __ATOMIC_RELAXED, __HIP_MEMORY_SCOPE_AGENT)

__device__ __forceinline__ float bf2f(u32 b){ union{u32 u; float f;} v; v.u = b<<16; return v.f; }
__device__ __forceinline__ u16 f2bf(float f){ union{float f; u32 u;} v; v.f = f; u32 u = v.u;
  return (u16)((u + 0x7fffu + ((u>>16)&1u)) >> 16); }
__device__ __forceinline__ u32 pack_f(float v){
  u16 hi = f2bf(v); u16 lo = f2bf(v - bf2f(hi)); return (u32)hi | ((u32)lo<<16); }

__device__ __forceinline__ void unpack8(uint4 a, uint4 b, short8& hi, short8& lo){
  u32 w[8] = {a.x,a.y,a.z,a.w,b.x,b.y,b.z,b.w};
#pragma unroll
  for (int j=0;j<8;++j){ hi[j] = (short)(w[j] & 0xffffu); lo[j] = (short)(w[j] >> 16); }
}
// 2 u64 = 4 u32 = 8 consecutive bf16 (hi-only h plane)
__device__ __forceinline__ void unpackh(u64 q0, u64 q1, short8& hi){
  u32 w[4] = {(u32)q0,(u32)(q0>>32),(u32)q1,(u32)(q1>>32)};
#pragma unroll
  for (int i=0;i<4;++i){ hi[2*i] = (short)(w[i] & 0xffffu); hi[2*i+1] = (short)(w[i] >> 16); }
}

// ---------------- workspace layout (bytes) — identical to R3 ----------------
constexpr size_t OFF_Y    = 0;            // u32[1000][32][256]; reused as out2 [250][32][1024]
constexpr size_t OFF_SUB  = 32768000;     // u32[250][32][1024]
constexpr size_t OFF_W0XH = 65536000;
constexpr size_t OFF_W0XL = 67108864;
constexpr size_t OFF_W0HH = 68681728;
constexpr size_t OFF_W0HL = 74973184;
constexpr size_t OFF_W1XH = 81264640;
constexpr size_t OFF_W1XL = 87556096;
constexpr size_t OFF_W1HH = 93847552;
constexpr size_t OFF_W1HL = 100139008;
constexpr size_t OFF_HB0  = 106430464;    // bf16 plane u16[2][32][1024] = 131072 B (in 262144 slot)
constexpr size_t OFF_HB1  = 106692608;
constexpr size_t OFF_FL0  = 106954752;    // int[256] pad 1KB
constexpr size_t OFF_FL1  = 106955776;
constexpr size_t WS_NEED  = 106956800;

// ---------------- weight fragment builder (compact 12-col; R3-proven) ----------------
// blob: [wg=256][kq=8][kt=K/256][kseg=4][c=12][j=8] u16
// k = kq*(K/8) + kt*32 + kseg*8 + j ; col = (c>>2)*1024 + wg*4 + (c&3)
__global__ void build_frags(const float* __restrict__ W, u16* __restrict__ fhi,
                            u16* __restrict__ flo, int K){
  const int KT = K >> 8;
  size_t total = (size_t)K * 12 * 256;
  for (size_t i = (size_t)blockIdx.x*blockDim.x + threadIdx.x; i < total;
       i += (size_t)gridDim.x*blockDim.x){
    int j = (int)(i & 7); size_t r = i >> 3;
    int c = (int)(r % 12); r /= 12;
    int kseg = (int)(r & 3); r >>= 2;
    int kt = (int)(r % KT); r /= KT;
    int kq = (int)(r & 7); r >>= 3;
    int wg = (int)r;
    int k = kq*(K>>3) + kt*32 + kseg*8 + j;
    int col = (c>>2)*1024 + wg*4 + (c&3);
    float v = W[(size_t)k*3072 + col];
    u16 hi = f2bf(v);
    u16 lo = f2bf(v - bf2f(hi));
    fhi[i] = hi; flo[i] = lo;
  }
}

// ---------------- init h0 + flags (h plane = bf16-hi pairs packed in u32) ----------------
__global__ void init_state(const float* __restrict__ h0, u32* hb0, u32* hb1,
                           int* f0, int* f1){
  int i = blockIdx.x*blockDim.x + threadIdx.x;
  if (i < 256){ f0[i]=0; f1[i]=0; }
  if (i < 16384){               // slot 0: [32][512] u32 = pairs of units
    int p = i & 511;
    u32 v = (u32)f2bf(h0[2*p]) | ((u32)f2bf(h0[2*p+1]) << 16);
    hb0[i] = v;
    hb1[i] = 0u;
  }
}

// ---------------- conv + relu + pack ----------------
__global__ void conv_pack(const float* __restrict__ x, const float* __restrict__ cw,
                          u32* __restrict__ yp){
  for (size_t i = (size_t)blockIdx.x*blockDim.x + threadIdx.x; i < 8192000ull;
       i += (size_t)gridDim.x*blockDim.x){
    int f = (int)(i & 255); int b = (int)((i>>8)&31); int t = (int)(i>>13);
    const float* xb = x + ((size_t)b*1000 + t)*256 + f;
    float acc = xb[0]*cw[256+f];
    if (t > 0)   acc += xb[-256]*cw[f];
    if (t < 999) acc += xb[256]*cw[512+f];
    acc = fmaxf(acc, 0.0f);
    yp[i] = pack_f(acc);
  }
}

// ---------------- persistent GRU layer (R3 structure; h broadcast = bf16-hi only) ----------------
// 256 WGs x 1024 threads. WG owns 4 units. Weights fully LDS-resident.
// h plane: u16[2][32][1024] (u32-pair packed). Broadcast bytes/step halved vs R3
// (16 MB vs 32 MB agent-LLC reads). Recurrent MFMA: Ahi*Bhi + Ahi*Blo (lo-of-h
// term dropped; contractive GRU error dynamics keep added error ~1e-3).
template<int LAYER>
__global__ __launch_bounds__(1024, 1)
void gru_persist(const u32* __restrict__ xin,
                 const u16* __restrict__ wxf_hi, const u16* __restrict__ wxf_lo,
                 const u16* __restrict__ whf_hi, const u16* __restrict__ whf_lo,
                 const float* __restrict__ bias,
                 u32* hbuf, int* flags, u32* out_pack)
{
  constexpr int T   = (LAYER==0) ? 1000 : 250;
  constexpr int KX  = (LAYER==0) ? 256 : 1024;
  constexpr int KTX = KX >> 8;
  __shared__ u16 WxHi[8*KTX*512], WxLo[8*KTX*512];
  __shared__ u16 WhHi[8*4*512],  WhLo[8*4*512];
  __shared__ float exch[8*32*18];
  __shared__ float harr[128];

  const int tid  = threadIdx.x;
  const int wg   = blockIdx.x;
  const int lane = tid & 63;
  const int wave = tid >> 6;
  const int m    = wave & 1;
  const int kq   = wave >> 1;
  const int u0   = wg * 4;
  const int lo16 = lane & 15, hi16 = lane >> 4;
  const int lane_off = hi16*128 + lo16*8;

  { // zero weight LDS (pad cols)
    for (int i = tid; i < 8*KTX*512/4; i += 1024){ ((u64*)WxHi)[i]=0; ((u64*)WxLo)[i]=0; }
    for (int i = tid; i < 8*4*512/4;  i += 1024){ ((u64*)WhHi)[i]=0; ((u64*)WhLo)[i]=0; }
  }
  __syncthreads();
  { // scatter compact blobs into padded LDS tiles (identical to R3)
    const u16* bx_hi = wxf_hi + (size_t)wg*KX*12;
    const u16* bx_lo = wxf_lo + (size_t)wg*KX*12;
    const u16* bh_hi = whf_hi + (size_t)wg*1024*12;
    const u16* bh_lo = whf_lo + (size_t)wg*1024*12;
    for (int i = tid; i < 8*KTX*48; i += 1024){
      int c = i % 12; int r = i/12; int kseg = r & 3; r >>= 2;
      int kt = r % KTX; int kqq = r / KTX;
      int ldsoff = ((kqq*KTX+kt)*4+kseg)*128 + c*8;            // [z r xh 0]
      *(short8*)&WxHi[ldsoff] = *(const short8*)&bx_hi[(size_t)i*8];
      *(short8*)&WxLo[ldsoff] = *(const short8*)&bx_lo[(size_t)i*8];
    }
    for (int i = tid; i < 8*4*48; i += 1024){
      int c = i % 12; int r = i/12; int kseg = r & 3; r >>= 2;
      int kt = r & 3; int kqq = r >> 2;
      int cm = (c < 8) ? c : (c + 4);                          // [z r 0 rh]
      int ldsoff = ((kqq*4+kt)*4+kseg)*128 + cm*8;
      *(short8*)&WhHi[ldsoff] = *(const short8*)&bh_hi[(size_t)i*8];
      *(short8*)&WhLo[ldsoff] = *(const short8*)&bh_lo[(size_t)i*8];
    }
    if (tid < 128){   // local fp32 h state from slot-0 bf16 plane
      u16 hv = ((const u16*)hbuf)[(tid>>2)*1024 + u0 + (tid&3)];
      harr[tid] = bf2f((u32)hv);
    }
  }
  __syncthreads();

  const int eb = tid >> 2, eu_l = tid & 3, eu = u0 + eu_l;
  const float zb  = bias[eu]        + bias[3072 + eu];
  const float rbv = bias[1024 + eu] + bias[4096 + eu];
  const float hxb = bias[2048 + eu];
  const float hrb = bias[5120 + eu];

  for (int t = 0; t < T; ++t) {
    const int cur = t & 1, nxt = cur ^ 1;
    f32x4 xacc = (f32x4){0.f,0.f,0.f,0.f};
    f32x4 racc = (f32x4){0.f,0.f,0.f,0.f};
    { // xproj (h-independent; overlaps laggard flag propagation) — unchanged R3
      const u32* xrow = xin + ((size_t)t*32 + 16*m + lo16)*KX + kq*(KX>>3) + hi16*8;
#pragma unroll
      for (int kt = 0; kt < KTX; ++kt) {
        uint4 a0 = *(const uint4*)(xrow + kt*32);
        uint4 a1 = *(const uint4*)(xrow + kt*32 + 4);
        short8 ahi, alo; unpack8(a0, a1, ahi, alo);
        short8 bhi = *(const short8*)&WxHi[(kq*KTX+kt)*512 + lane_off];
        short8 blo = *(const short8*)&WxLo[(kq*KTX+kt)*512 + lane_off];
        xacc = MFMA(ahi, bhi, xacc);
        xacc = MFMA(alo, bhi, xacc);
        xacc = MFMA(ahi, blo, xacc);
      }
    }
    // wait for h_t: wave 0 polls all 256 flags (proven R3 pattern)
    if (t > 0) {
      if (wave == 0) {
        int f0,f1,f2,f3;
        do {
          f0 = ALOAD32(flags + lane);       f1 = ALOAD32(flags + 64 + lane);
          f2 = ALOAD32(flags + 128 + lane); f3 = ALOAD32(flags + 192 + lane);
        } while (!__all(f0 >= t && f1 >= t && f2 >= t && f3 >= t));
      }
      __syncthreads();
    }
    { // recurrent: h(t) bf16-hi slice @ Wh tile — half the bytes, 2 MFMAs/tile
      const u32* hrow = hbuf + cur*16384 + (16*m + lo16)*512 + kq*64 + hi16*4;
      u64 q[8];
#pragma unroll
      for (int kt = 0; kt < 4; ++kt){
        const u64* hq = (const u64*)(hrow + kt*16);
        q[kt*2]   = ALOAD64(hq);
        q[kt*2+1] = ALOAD64(hq + 1);
      }
#pragma unroll
      for (int kt = 0; kt < 4; ++kt) {
        short8 ahi; unpackh(q[kt*2], q[kt*2+1], ahi);
        short8 bhi = *(const short8*)&WhHi[(kq*4+kt)*512 + lane_off];
        short8 blo = *(const short8*)&WhLo[(kq*4+kt)*512 + lane_off];
        racc = MFMA(ahi, bhi, racc);
        racc = MFMA(ahi, blo, racc);
      }
    }
    { // exchange partials: D layout col=lane&15, row=(lane>>4)*4+r
      const int bb = 16*m + hi16*4;
#pragma unroll
      for (int r4 = 0; r4 < 4; ++r4)
        exch[(kq*32 + bb + r4)*18 + lo16] = xacc[r4] + racc[r4];
    }
    __syncthreads();
    if (tid < 128) { // gates: one (b,unit) per thread (R3 mapping)
      float zp=0.f, rp=0.f, xh=0.f, rh=0.f;
#pragma unroll
      for (int qd = 0; qd < 8; ++qd) {
        const float* e = &exch[(qd*32 + eb)*18];
        zp += e[eu_l];
        rp += e[4 + eu_l];
        xh += e[8 + eu_l];
        rh += e[12 + eu_l];
      }
      float z = 1.f/(1.f + __expf(-(zp + zb)));
      float r = 1.f/(1.f + __expf(-(rp + rbv)));
      float pre = xh + hxb + r*(rh + hrb);
      float ex = __expf(-2.f*fabsf(pre));
      float th = (1.f - ex)/(1.f + ex);
      float hh = copysignf(th, pre);
      float hn = z*harr[tid] + (1.f - z)*hh;
      harr[tid] = hn;
      // out_pack keeps the packed {hi,lo} format (consumed by next kernel)
      u32 pk = pack_f(hn);
      if (LAYER==0) {
        if ((t & 3) == 0)
          out_pack[((size_t)(t>>2)*32 + eb)*1024 + u0 + eu_l] = pk;
      } else {
        out_pack[((size_t)t*32 + eb)*1024 + u0 + eu_l] = pk;
      }
      // h broadcast: bf16-hi only, two units packed per u32, even lane stores
      int pk16 = (int)(pk & 0xffffu);               // f2bf(hn)
      int prt  = __shfl_xor(pk16, 1);               // partner unit (eu_l^1)
      if ((tid & 1) == 0) {
        u32 pair = (u32)pk16 | ((u32)prt << 16);    // low = even unit
        ASTORE32(hbuf + nxt*16384 + eb*512 + wg*2 + (eu_l>>1), pair);
      }
    }
    asm volatile("s_waitcnt vmcnt(0)" ::: "memory");   // own stores acked at LLC
    __syncthreads();                                   // => whole WG's stores acked
    if (tid == 0)
      ASTORE32(flags + wg, t+1);
  }
}

// ---------------- final dense head ----------------
__global__ __launch_bounds__(256, 1)
void dense_k(const u32* __restrict__ h2, const float* __restrict__ W,
             const float* __restrict__ bias, float* __restrict__ out){
  __shared__ float rows[32*1025];
  const int ts = blockIdx.x;
  const u32* src = h2 + (size_t)ts*32768;
  for (int i = threadIdx.x; i < 32768; i += 256){
    u32 p = src[i];
    rows[(i>>10)*1025 + (i&1023)] = bf2f(p & 0xffffu) + bf2f(p >> 16);
  }
  __syncthreads();
  const int b = threadIdx.x >> 3, cg = threadIdx.x & 7;
  float acc[6] = {0.f,0.f,0.f,0.f,0.f,0.f};
  for (int k = 0; k < 1024; ++k){
    float hv = rows[b*1025 + k];
    const float* wr = W + k*41;
#pragma unroll
    for (int j = 0; j < 6; ++j){ int c = cg + 8*j; if (c < 41) acc[j] += hv*wr[c]; }
  }
#pragma unroll
  for (int j = 0; j < 6; ++j){
    int c = cg + 8*j;
    if (c < 41) out[((size_t)b*250 + ts)*41 + c] = acc[j] + bias[c];
  }
}

// ---------------- launch ----------------
extern "C" void kernel_launch(void* const* d_in, const int* in_sizes, int n_in,
                              void* d_out, int out_size, void* d_ws, size_t ws_size,
                              hipStream_t stream) {
  const float* x      = (const float*)d_in[0];
  const float* conv_w = (const float*)d_in[1];
  const float* h0i    = (const float*)d_in[2];
  const float* w0x    = (const float*)d_in[3];
  const float* w0h    = (const float*)d_in[4];
  const float* b0     = (const float*)d_in[5];
  const float* w1x    = (const float*)d_in[6];
  const float* w1h    = (const float*)d_in[7];
  const float* b1     = (const float*)d_in[8];
  const float* dw     = (const float*)d_in[9];
  const float* db     = (const float*)d_in[10];
  float* outp = (float*)d_out;

  if (ws_size < WS_NEED) return;  // workspace too small: leave output poisoned

  char* ws = (char*)d_ws;
  u32* y_pack   = (u32*)(ws + OFF_Y);
  u32* out2     = (u32*)(ws + OFF_Y);      // reuse after y_pack is dead
  u32* sub_pack = (u32*)(ws + OFF_SUB);
  u16* w0x_hi = (u16*)(ws + OFF_W0XH); u16* w0x_lo = (u16*)(ws + OFF_W0XL);
  u16* w0h_hi = (u16*)(ws + OFF_W0HH); u16* w0h_lo = (u16*)(ws + OFF_W0HL);
  u16* w1x_hi = (u16*)(ws + OFF_W1XH); u16* w1x_lo = (u16*)(ws + OFF_W1XL);
  u16* w1h_hi = (u16*)(ws + OFF_W1HH); u16* w1h_lo = (u16*)(ws + OFF_W1HL);
  u32* hb0 = (u32*)(ws + OFF_HB0);
  u32* hb1 = (u32*)(ws + OFF_HB1);
  int* fl0 = (int*)(ws + OFF_FL0);
  int* fl1 = (int*)(ws + OFF_FL1);

  init_state<<<64, 512, 0, stream>>>(h0i, hb0, hb1, fl0, fl1);
  build_frags<<<2048, 256, 0, stream>>>(w0x, w0x_hi, w0x_lo, 256);
  build_frags<<<2048, 256, 0, stream>>>(w0h, w0h_hi, w0h_lo, 1024);
  build_frags<<<2048, 256, 0, stream>>>(w1x, w1x_hi, w1x_lo, 1024);
  build_frags<<<2048, 256, 0, stream>>>(w1h, w1h_hi, w1h_lo, 1024);
  conv_pack<<<4096, 256, 0, stream>>>(x, conv_w, y_pack);

  gru_persist<0><<<256, 1024, 0, stream>>>(y_pack, w0x_hi, w0x_lo, w0h_hi, w0h_lo,
                                           b0, hb0, fl0, sub_pack);
  gru_persist<1><<<256, 1024, 0, stream>>>(sub_pack, w1x_hi, w1x_lo, w1h_hi, w1h_lo,
                                           b1, hb1, fl1, out2);

  dense_k<<<250, 256, 0, stream>>>(out2, dw, db, outp);
}